// Round 5
// baseline (512.843 us; speedup 1.0000x reference)
//
#include <hip/hip_runtime.h>
#include <math.h>

typedef __attribute__((ext_vector_type(4))) float f32x4;
typedef __attribute__((ext_vector_type(4))) float f4;
typedef __attribute__((ext_vector_type(8))) _Float16 h8;
typedef __attribute__((ext_vector_type(8))) unsigned short us8;

static __device__ __forceinline__ h8 ld8h(const _Float16* p) {
    return __builtin_bit_cast(h8, *(const us8*)p);
}
static __device__ __forceinline__ void glds16(const void* g, void* l) {
    __builtin_amdgcn_global_load_lds((const __attribute__((address_space(1))) unsigned int*)g,
                                     (__attribute__((address_space(3))) unsigned int*)l, 16, 0, 0);
}

// ---------------------------------------------------------------------------
// fp32 -> fp16, 8 elements/thread
// ---------------------------------------------------------------------------
__global__ void convert_half(const float* __restrict__ in, _Float16* __restrict__ out, int n8) {
    int i = blockIdx.x * blockDim.x + threadIdx.x;
    if (i >= n8) return;
    f4 v0 = *(const f4*)(in + (size_t)i * 8);
    f4 v1 = *(const f4*)(in + (size_t)i * 8 + 4);
    h8 o;
#pragma unroll
    for (int j = 0; j < 4; j++) {
        o[j] = (_Float16)v0[j];
        o[j + 4] = (_Float16)v1[j];
    }
    *(h8*)(out + (size_t)i * 8) = o;
}

// ---------------------------------------------------------------------------
// C = A @ B^T fp16 MFMA: A[M][K], B[N][K] fp16, C[M][N] fp32
// 128x128 tile, BK=32, double-buffered LDS, ONE barrier per K-step:
//   barrier -> issue glds(t+1 -> buf^1) -> ds_read+MFMA on buf -> loop
// ---------------------------------------------------------------------------
__global__ __launch_bounds__(256, 3) void gemm_fp16(
    const _Float16* __restrict__ A, const _Float16* __restrict__ B,
    float* __restrict__ C, int M, int N, int K) {
    __shared__ _Float16 As[2][128][32], Bs[2][128][32];
    const int t = threadIdx.x;
    const int lane = t & 63, w = t >> 6;
    const int bm = blockIdx.y * 128, bn = blockIdx.x * 128;
    const int wy = w >> 1, wx = w & 1;
    const int l15 = lane & 15, l4 = lane >> 4;

    // staging geometry: 2 chunks per thread per array; chunk c covers
    // row=c>>2, seg=(c&3)*8; LDS dest = base + c*16B (wave-uniform + lane*16)
    const int c0 = (w * 2 + 0) * 64 + lane;
    const int c1 = (w * 2 + 1) * 64 + lane;
    const int r0s = c0 >> 2, s0 = (c0 & 3) * 8;
    const int r1s = c1 >> 2, s1 = (c1 & 3) * 8;

    f32x4 acc[4][4] = {};

    // prologue: stage k0=0 into buf 0
    glds16(A + (size_t)(bm + r0s) * K + s0, &As[0][0][0] + c0 * 8);
    glds16(A + (size_t)(bm + r1s) * K + s1, &As[0][0][0] + c1 * 8);
    glds16(B + (size_t)(bn + r0s) * K + s0, &Bs[0][0][0] + c0 * 8);
    glds16(B + (size_t)(bn + r1s) * K + s1, &Bs[0][0][0] + c1 * 8);

    int cur = 0;
    for (int k0 = 0; k0 < K; k0 += 32) {
        __syncthreads();  // drains vmcnt: buf[cur] ready
        const int nk = k0 + 32;
        if (nk < K) {
            _Float16* an = &As[cur ^ 1][0][0];
            _Float16* bn_ = &Bs[cur ^ 1][0][0];
            glds16(A + (size_t)(bm + r0s) * K + nk + s0, an + c0 * 8);
            glds16(A + (size_t)(bm + r1s) * K + nk + s1, an + c1 * 8);
            glds16(B + (size_t)(bn + r0s) * K + nk + s0, bn_ + c0 * 8);
            glds16(B + (size_t)(bn + r1s) * K + nk + s1, bn_ + c1 * 8);
        }
        h8 af[4], bf[4];
#pragma unroll
        for (int m = 0; m < 4; m++) af[m] = ld8h(&As[cur][wy * 64 + m * 16 + l15][l4 * 8]);
#pragma unroll
        for (int n = 0; n < 4; n++) bf[n] = ld8h(&Bs[cur][wx * 64 + n * 16 + l15][l4 * 8]);
#pragma unroll
        for (int m = 0; m < 4; m++)
#pragma unroll
            for (int n = 0; n < 4; n++)
                acc[m][n] = __builtin_amdgcn_mfma_f32_16x16x32_f16(af[m], bf[n], acc[m][n], 0, 0, 0);
        cur ^= 1;
    }

#pragma unroll
    for (int m = 0; m < 4; m++)
#pragma unroll
        for (int n = 0; n < 4; n++)
#pragma unroll
            for (int r = 0; r < 4; r++)
                C[(size_t)(bm + wy * 64 + m * 16 + l4 * 4 + r) * N + bn + wx * 64 + n * 16 + l15] =
                    acc[m][n][r];
}

// ---------------------------------------------------------------------------
// SuRoPE on q,k from fused qkv; fp16 out [H][L][96]; ATTN_SCALE folded into Q.
// ---------------------------------------------------------------------------
__global__ void rope_half(const float* __restrict__ qkv, const float* __restrict__ sf,
                          _Float16* __restrict__ Qh, _Float16* __restrict__ Kh,
                          float rope_scale, float attn_scale) {
    int idx = blockIdx.x * blockDim.x + threadIdx.x;  // 2*32*2048*96
    const int d = idx % 96;
    int r = idx / 96;
    const int l = r % 2048; r /= 2048;
    const int h = r % 32;
    const int which = r / 32;  // 0=q, 1=k
    const size_t base = (size_t)l * 9216 + (size_t)which * 3072 + h * 96;
    const float val = qkv[base + d];
    const int j = (d < 48) ? d : d - 48;
    const float e = (float)(2 * j) / 96.0f;
    const float inv = 1.0f / (sf[j] * powf(10000.0f, e));
    const float ang = (float)l * inv;
    const float cv = cosf(ang) * rope_scale;
    const float sv = sinf(ang) * rope_scale;
    const float pair = qkv[base + ((d < 48) ? d + 48 : d - 48)];
    const float rot = (d < 48) ? -pair : pair;
    float out = val * cv + rot * sv;
    if (which == 0) out *= attn_scale;
    const size_t dst = ((size_t)h * 2048 + l) * 96 + d;
    if (which == 0) Qh[dst] = (_Float16)out;
    else            Kh[dst] = (_Float16)out;
}

// ---------------------------------------------------------------------------
// V transpose: qkv v-part [l][h*96+d] -> Vt[h][d][l] fp16
// ---------------------------------------------------------------------------
__global__ __launch_bounds__(256) void vtrans(const float* __restrict__ qkv,
                                              _Float16* __restrict__ Vt) {
    __shared__ float tile[64][100];
    const int h = blockIdx.y;
    const int l0 = blockIdx.x * 64;
    const int t = threadIdx.x;
#pragma unroll
    for (int i = 0; i < 6; i++) {
        const int v = t + i * 256;
        const int row = v / 24, seg = v % 24;
        *(f4*)&tile[row][seg * 4] =
            *(const f4*)(qkv + (size_t)(l0 + row) * 9216 + 6144 + h * 96 + seg * 4);
    }
    __syncthreads();
#pragma unroll
    for (int i = 0; i < 3; i++) {
        const int v = t + i * 256;
        const int d = v >> 3, lc = v & 7;
        h8 o;
#pragma unroll
        for (int j = 0; j < 8; j++) o[j] = (_Float16)tile[lc * 8 + j][d];
        *(h8*)(Vt + ((size_t)h * 96 + d) * 2048 + l0 + lc * 8) = o;
    }
}

// ---------------------------------------------------------------------------
// Flash attention, fp16 MFMA. Block = (64 q-rows, head), 4 waves x 16 rows.
// K/V double-buffered with async reg-staging (T14 split): issue next tile's
// global loads right after the barrier; ds_write them at the next iteration.
// One barrier per KV tile.
// ---------------------------------------------------------------------------
__global__ __launch_bounds__(256, 2) void attn_mfma(
    const _Float16* __restrict__ Qh, const _Float16* __restrict__ Kh,
    const _Float16* __restrict__ Vt, _Float16* __restrict__ Oh) {
    __shared__ _Float16 Ks[2][64][104];
    __shared__ _Float16 Vs[2][96][72];
    __shared__ _Float16 Ps[4][16][72];

    const int h = blockIdx.y;
    const int qt = (int)gridDim.x - 1 - (int)blockIdx.x;  // heavy blocks first
    const int q0 = qt * 64;
    const int t = threadIdx.x, lane = t & 63, w = t >> 6;
    const int l15 = lane & 15, l4 = lane >> 4;

    const _Float16* Kg = Kh + (size_t)h * 2048 * 96;
    const _Float16* Vg = Vt + (size_t)h * 96 * 2048;

    h8 qf[3];
    const size_t qrow = ((size_t)h * 2048 + q0 + w * 16 + l15) * 96;
#pragma unroll
    for (int kc = 0; kc < 3; kc++) qf[kc] = ld8h(Qh + qrow + kc * 32 + l4 * 8);

    // prologue: load tile 0 into regs
    us8 kreg[3], vreg[3];
#pragma unroll
    for (int i = 0; i < 3; i++) {
        const int c = t + i * 256;
        kreg[i] = *(const us8*)(Kg + (size_t)(c / 12) * 96 + (c % 12) * 8);
        vreg[i] = *(const us8*)(Vg + (size_t)(c >> 3) * 2048 + (c & 7) * 8);
    }

    f32x4 o[6] = {};
    float m_i[4] = {-1e30f, -1e30f, -1e30f, -1e30f};
    float l_i[4] = {0.f, 0.f, 0.f, 0.f};

    for (int kt = 0; kt <= qt; kt++) {
        const int buf = kt & 1;
        // write staged regs into LDS buf
#pragma unroll
        for (int i = 0; i < 3; i++) {
            const int c = t + i * 256;
            *(us8*)&Ks[buf][c / 12][(c % 12) * 8] = kreg[i];
            *(us8*)&Vs[buf][c >> 3][(c & 7) * 8] = vreg[i];
        }
        __syncthreads();
        if (kt < qt) {  // issue next tile's loads; latency hides under compute
            const int kv1 = (kt + 1) * 64;
#pragma unroll
            for (int i = 0; i < 3; i++) {
                const int c = t + i * 256;
                kreg[i] = *(const us8*)(Kg + (size_t)(kv1 + c / 12) * 96 + (c % 12) * 8);
                vreg[i] = *(const us8*)(Vg + (size_t)(c >> 3) * 2048 + kv1 + (c & 7) * 8);
            }
        }

        // S = Q K^T
        f32x4 s[4] = {};
#pragma unroll
        for (int f = 0; f < 4; f++)
#pragma unroll
            for (int kc = 0; kc < 3; kc++) {
                h8 kf = ld8h(&Ks[buf][f * 16 + l15][kc * 32 + l4 * 8]);
                s[f] = __builtin_amdgcn_mfma_f32_16x16x32_f16(qf[kc], kf, s[f], 0, 0, 0);
            }

        if (kt == qt) {  // causal mask on diagonal tile
#pragma unroll
            for (int f = 0; f < 4; f++)
#pragma unroll
                for (int r = 0; r < 4; r++)
                    if (f * 16 + l15 > w * 16 + l4 * 4 + r) s[f][r] = -1e30f;
        }

        // online softmax (rows = l4*4+r, cols spread over l15 and f)
        float pr[4][4], sc[4];
#pragma unroll
        for (int r = 0; r < 4; r++) {
            float mx = fmaxf(fmaxf(s[0][r], s[1][r]), fmaxf(s[2][r], s[3][r]));
#pragma unroll
            for (int msk = 1; msk < 16; msk <<= 1) mx = fmaxf(mx, __shfl_xor(mx, msk, 64));
            const float mnew = fmaxf(m_i[r], mx);
            sc[r] = __expf(m_i[r] - mnew);
            m_i[r] = mnew;
            float ssum = 0.f;
#pragma unroll
            for (int f = 0; f < 4; f++) {
                const float p = __expf(s[f][r] - mnew);
                pr[f][r] = p;
                ssum += p;
            }
#pragma unroll
            for (int msk = 1; msk < 16; msk <<= 1) ssum += __shfl_xor(ssum, msk, 64);
            l_i[r] = l_i[r] * sc[r] + ssum;
        }
#pragma unroll
        for (int f2 = 0; f2 < 6; f2++)
#pragma unroll
            for (int r = 0; r < 4; r++) o[f2][r] *= sc[r];

        // store P (fp16, per-wave buffer: no barrier needed)
#pragma unroll
        for (int f = 0; f < 4; f++)
#pragma unroll
            for (int r = 0; r < 4; r++)
                Ps[w][l4 * 4 + r][f * 16 + l15] = (_Float16)pr[f][r];

        // O += P V   (K = 64)
#pragma unroll
        for (int kc2 = 0; kc2 < 2; kc2++) {
            h8 pa = ld8h(&Ps[w][l15][kc2 * 32 + l4 * 8]);
#pragma unroll
            for (int f2 = 0; f2 < 6; f2++) {
                h8 vb = ld8h(&Vs[buf][f2 * 16 + l15][kc2 * 32 + l4 * 8]);
                o[f2] = __builtin_amdgcn_mfma_f32_16x16x32_f16(pa, vb, o[f2], 0, 0, 0);
            }
        }
    }

    // epilogue: normalize, write fp16 O [L][3072]
#pragma unroll
    for (int r = 0; r < 4; r++) {
        const float inv = 1.0f / l_i[r];
        const size_t row = (size_t)(q0 + w * 16 + l4 * 4 + r) * 3072 + h * 96;
#pragma unroll
        for (int f2 = 0; f2 < 6; f2++)
            Oh[row + f2 * 16 + l15] = (_Float16)(o[f2][r] * inv);
    }
}

// ---------------------------------------------------------------------------
extern "C" void kernel_launch(void* const* d_in, const int* in_sizes, int n_in,
                              void* d_out, int out_size, void* d_ws, size_t ws_size,
                              hipStream_t stream) {
    const float* x = (const float*)d_in[0];
    const float* w_qkv = (const float*)d_in[1];
    const float* w_o = (const float*)d_in[2];
    const float* sf = (const float*)d_in[3];
    float* out = (float*)d_out;
    char* ws = (char*)d_ws;

    // region A [0, 56.6MB): wqkv fp16; dead after GEMM1, reused for Q/K/V/O
    _Float16* wqkvh = (_Float16*)(ws);
    _Float16* Qh = (_Float16*)(ws);
    _Float16* Kh = (_Float16*)(ws + 12582912);
    _Float16* Vth = (_Float16*)(ws + 25165824);
    _Float16* Oh = (_Float16*)(ws + 37748736);
    // region B: qkv fp32
    float* qkv = (float*)(ws + 56623104);
    // region C: x fp16
    _Float16* xh = (_Float16*)(ws + 132120576);
    // region D: w_o fp16
    _Float16* woh = (_Float16*)(ws + 144703488);

    const float rope_scale = (float)sqrt(1.0 + log(131072.0 / 4096.0) / log(4096.0));
    const float attn_scale = (float)(1.0 / sqrt(96.0));

    convert_half<<<3072, 256, 0, stream>>>(x, xh, 786432);
    convert_half<<<13824, 256, 0, stream>>>(w_qkv, wqkvh, 3538944);
    gemm_fp16<<<dim3(72, 16), 256, 0, stream>>>(xh, wqkvh, qkv, 2048, 9216, 3072);
    rope_half<<<49152, 256, 0, stream>>>(qkv, sf, Qh, Kh, rope_scale, attn_scale);
    vtrans<<<dim3(32, 32), 256, 0, stream>>>(qkv, Vth);
    convert_half<<<4608, 256, 0, stream>>>(w_o, woh, 1179648);
    attn_mfma<<<dim3(32, 32), 256, 0, stream>>>(Qh, Kh, Vth, Oh);
    gemm_fp16<<<dim3(24, 16), 256, 0, stream>>>(Oh, woh, out, 2048, 3072, 3072);
}

// Round 6
// 502.844 us; speedup vs baseline: 1.0199x; 1.0199x over previous
//
#include <hip/hip_runtime.h>
#include <math.h>

typedef __attribute__((ext_vector_type(4))) float f32x4;
typedef __attribute__((ext_vector_type(4))) float f4;
typedef __attribute__((ext_vector_type(8))) _Float16 h8;
typedef __attribute__((ext_vector_type(8))) unsigned short us8;

static __device__ __forceinline__ h8 ld8h(const _Float16* p) {
    return __builtin_bit_cast(h8, *(const us8*)p);
}
static __device__ __forceinline__ void glds16(const void* g, void* l) {
    __builtin_amdgcn_global_load_lds((const __attribute__((address_space(1))) unsigned int*)g,
                                     (__attribute__((address_space(3))) unsigned int*)l, 16, 0, 0);
}

// ---------------------------------------------------------------------------
// fp32 -> fp16, 8 elements/thread
// ---------------------------------------------------------------------------
__global__ void convert_half(const float* __restrict__ in, _Float16* __restrict__ out, int n8) {
    int i = blockIdx.x * blockDim.x + threadIdx.x;
    if (i >= n8) return;
    f4 v0 = *(const f4*)(in + (size_t)i * 8);
    f4 v1 = *(const f4*)(in + (size_t)i * 8 + 4);
    h8 o;
#pragma unroll
    for (int j = 0; j < 4; j++) {
        o[j] = (_Float16)v0[j];
        o[j + 4] = (_Float16)v1[j];
    }
    *(h8*)(out + (size_t)i * 8) = o;
}

// ---------------------------------------------------------------------------
// C = A @ B^T fp16 MFMA: A[M][K], B[N][K] fp16, C[M][N] fp32
// 128x128 tile, BK=32, dbuf LDS, one barrier per K-step.
// LDS bank-conflict fix (T2, rule #21): row-major [128][32] fp16 has 64B row
// stride -> fragment reads are 8-way conflicted. XOR-swizzle 16B slot index
// with ((row>>1)&3): applied on the GLOBAL source address (linear LDS dest,
// required by global_load_lds) and on the LDS read side. 2-way = free.
// ---------------------------------------------------------------------------
__global__ __launch_bounds__(256, 3) void gemm_fp16(
    const _Float16* __restrict__ A, const _Float16* __restrict__ B,
    float* __restrict__ C, int M, int N, int K) {
    __shared__ _Float16 As[2][128][32], Bs[2][128][32];
    const int t = threadIdx.x;
    const int lane = t & 63, w = t >> 6;
    const int bm = blockIdx.y * 128, bn = blockIdx.x * 128;
    const int wy = w >> 1, wx = w & 1;
    const int l15 = lane & 15, l4 = lane >> 4;

    // staging geometry: chunk c (16B) -> LDS row=c>>2, slot=c&3 (linear);
    // source global slot = (c&3) ^ ((row>>1)&3)  [inverse swizzle]
    const int c0 = (w * 2 + 0) * 64 + lane;
    const int c1 = (w * 2 + 1) * 64 + lane;
    const int r0s = c0 >> 2, s0 = (((c0 & 3) ^ ((r0s >> 1) & 3)) * 8);
    const int r1s = c1 >> 2, s1 = (((c1 & 3) ^ ((r1s >> 1) & 3)) * 8);

    f32x4 acc[4][4] = {};

    glds16(A + (size_t)(bm + r0s) * K + s0, &As[0][0][0] + c0 * 8);
    glds16(A + (size_t)(bm + r1s) * K + s1, &As[0][0][0] + c1 * 8);
    glds16(B + (size_t)(bn + r0s) * K + s0, &Bs[0][0][0] + c0 * 8);
    glds16(B + (size_t)(bn + r1s) * K + s1, &Bs[0][0][0] + c1 * 8);

    // read-side swizzled column offsets (elements): depends on row parity pair
    int cry[4], crx[4];
#pragma unroll
    for (int m = 0; m < 4; m++) {
        const int rowA = wy * 64 + m * 16 + l15;
        cry[m] = ((l4 ^ ((rowA >> 1) & 3)) * 8);
        const int rowB = wx * 64 + m * 16 + l15;
        crx[m] = ((l4 ^ ((rowB >> 1) & 3)) * 8);
    }

    int cur = 0;
    for (int k0 = 0; k0 < K; k0 += 32) {
        __syncthreads();  // buf[cur] ready
        const int nk = k0 + 32;
        if (nk < K) {
            _Float16* an = &As[cur ^ 1][0][0];
            _Float16* bn_ = &Bs[cur ^ 1][0][0];
            glds16(A + (size_t)(bm + r0s) * K + nk + s0, an + c0 * 8);
            glds16(A + (size_t)(bm + r1s) * K + nk + s1, an + c1 * 8);
            glds16(B + (size_t)(bn + r0s) * K + nk + s0, bn_ + c0 * 8);
            glds16(B + (size_t)(bn + r1s) * K + nk + s1, bn_ + c1 * 8);
        }
        h8 af[4], bf[4];
#pragma unroll
        for (int m = 0; m < 4; m++) af[m] = ld8h(&As[cur][wy * 64 + m * 16 + l15][cry[m]]);
#pragma unroll
        for (int n = 0; n < 4; n++) bf[n] = ld8h(&Bs[cur][wx * 64 + n * 16 + l15][crx[n]]);
#pragma unroll
        for (int m = 0; m < 4; m++)
#pragma unroll
            for (int n = 0; n < 4; n++)
                acc[m][n] = __builtin_amdgcn_mfma_f32_16x16x32_f16(af[m], bf[n], acc[m][n], 0, 0, 0);
        cur ^= 1;
    }

#pragma unroll
    for (int m = 0; m < 4; m++)
#pragma unroll
        for (int n = 0; n < 4; n++)
#pragma unroll
            for (int r = 0; r < 4; r++)
                C[(size_t)(bm + wy * 64 + m * 16 + l4 * 4 + r) * N + bn + wx * 64 + n * 16 + l15] =
                    acc[m][n][r];
}

// ---------------------------------------------------------------------------
// SuRoPE on q,k from fused qkv; fp16 out [H][L][96]; ATTN_SCALE folded into Q.
// ---------------------------------------------------------------------------
__global__ void rope_half(const float* __restrict__ qkv, const float* __restrict__ sf,
                          _Float16* __restrict__ Qh, _Float16* __restrict__ Kh,
                          float rope_scale, float attn_scale) {
    int idx = blockIdx.x * blockDim.x + threadIdx.x;  // 2*32*2048*96
    const int d = idx % 96;
    int r = idx / 96;
    const int l = r % 2048; r /= 2048;
    const int h = r % 32;
    const int which = r / 32;  // 0=q, 1=k
    const size_t base = (size_t)l * 9216 + (size_t)which * 3072 + h * 96;
    const float val = qkv[base + d];
    const int j = (d < 48) ? d : d - 48;
    const float e = (float)(2 * j) / 96.0f;
    const float inv = 1.0f / (sf[j] * powf(10000.0f, e));
    const float ang = (float)l * inv;
    const float cv = cosf(ang) * rope_scale;
    const float sv = sinf(ang) * rope_scale;
    const float pair = qkv[base + ((d < 48) ? d + 48 : d - 48)];
    const float rot = (d < 48) ? -pair : pair;
    float out = val * cv + rot * sv;
    if (which == 0) out *= attn_scale;
    const size_t dst = ((size_t)h * 2048 + l) * 96 + d;
    if (which == 0) Qh[dst] = (_Float16)out;
    else            Kh[dst] = (_Float16)out;
}

// ---------------------------------------------------------------------------
// V transpose: qkv v-part [l][h*96+d] -> Vt[h][d][l] fp16
// ---------------------------------------------------------------------------
__global__ __launch_bounds__(256) void vtrans(const float* __restrict__ qkv,
                                              _Float16* __restrict__ Vt) {
    __shared__ float tile[64][100];
    const int h = blockIdx.y;
    const int l0 = blockIdx.x * 64;
    const int t = threadIdx.x;
#pragma unroll
    for (int i = 0; i < 6; i++) {
        const int v = t + i * 256;
        const int row = v / 24, seg = v % 24;
        *(f4*)&tile[row][seg * 4] =
            *(const f4*)(qkv + (size_t)(l0 + row) * 9216 + 6144 + h * 96 + seg * 4);
    }
    __syncthreads();
#pragma unroll
    for (int i = 0; i < 3; i++) {
        const int v = t + i * 256;
        const int d = v >> 3, lc = v & 7;
        h8 o;
#pragma unroll
        for (int j = 0; j < 8; j++) o[j] = (_Float16)tile[lc * 8 + j][d];
        *(h8*)(Vt + ((size_t)h * 96 + d) * 2048 + l0 + lc * 8) = o;
    }
}

// ---------------------------------------------------------------------------
// Flash attention, fp16 MFMA. Block = (64 q-rows, head), 4 waves x 16 rows.
// K/V double-buffered with async reg-staging; one barrier per KV tile.
// ---------------------------------------------------------------------------
__global__ __launch_bounds__(256, 2) void attn_mfma(
    const _Float16* __restrict__ Qh, const _Float16* __restrict__ Kh,
    const _Float16* __restrict__ Vt, _Float16* __restrict__ Oh) {
    __shared__ _Float16 Ks[2][64][104];
    __shared__ _Float16 Vs[2][96][72];
    __shared__ _Float16 Ps[4][16][72];

    const int h = blockIdx.y;
    const int qt = (int)gridDim.x - 1 - (int)blockIdx.x;  // heavy blocks first
    const int q0 = qt * 64;
    const int t = threadIdx.x, lane = t & 63, w = t >> 6;
    const int l15 = lane & 15, l4 = lane >> 4;

    const _Float16* Kg = Kh + (size_t)h * 2048 * 96;
    const _Float16* Vg = Vt + (size_t)h * 96 * 2048;

    h8 qf[3];
    const size_t qrow = ((size_t)h * 2048 + q0 + w * 16 + l15) * 96;
#pragma unroll
    for (int kc = 0; kc < 3; kc++) qf[kc] = ld8h(Qh + qrow + kc * 32 + l4 * 8);

    us8 kreg[3], vreg[3];
#pragma unroll
    for (int i = 0; i < 3; i++) {
        const int c = t + i * 256;
        kreg[i] = *(const us8*)(Kg + (size_t)(c / 12) * 96 + (c % 12) * 8);
        vreg[i] = *(const us8*)(Vg + (size_t)(c >> 3) * 2048 + (c & 7) * 8);
    }

    f32x4 o[6] = {};
    float m_i[4] = {-1e30f, -1e30f, -1e30f, -1e30f};
    float l_i[4] = {0.f, 0.f, 0.f, 0.f};

    for (int kt = 0; kt <= qt; kt++) {
        const int buf = kt & 1;
#pragma unroll
        for (int i = 0; i < 3; i++) {
            const int c = t + i * 256;
            *(us8*)&Ks[buf][c / 12][(c % 12) * 8] = kreg[i];
            *(us8*)&Vs[buf][c >> 3][(c & 7) * 8] = vreg[i];
        }
        __syncthreads();
        if (kt < qt) {
            const int kv1 = (kt + 1) * 64;
#pragma unroll
            for (int i = 0; i < 3; i++) {
                const int c = t + i * 256;
                kreg[i] = *(const us8*)(Kg + (size_t)(kv1 + c / 12) * 96 + (c % 12) * 8);
                vreg[i] = *(const us8*)(Vg + (size_t)(c >> 3) * 2048 + kv1 + (c & 7) * 8);
            }
        }

        // S = Q K^T
        f32x4 s[4] = {};
#pragma unroll
        for (int f = 0; f < 4; f++)
#pragma unroll
            for (int kc = 0; kc < 3; kc++) {
                h8 kf = ld8h(&Ks[buf][f * 16 + l15][kc * 32 + l4 * 8]);
                s[f] = __builtin_amdgcn_mfma_f32_16x16x32_f16(qf[kc], kf, s[f], 0, 0, 0);
            }

        if (kt == qt) {
#pragma unroll
            for (int f = 0; f < 4; f++)
#pragma unroll
                for (int r = 0; r < 4; r++)
                    if (f * 16 + l15 > w * 16 + l4 * 4 + r) s[f][r] = -1e30f;
        }

        float pr[4][4], sc[4];
#pragma unroll
        for (int r = 0; r < 4; r++) {
            float mx = fmaxf(fmaxf(s[0][r], s[1][r]), fmaxf(s[2][r], s[3][r]));
#pragma unroll
            for (int msk = 1; msk < 16; msk <<= 1) mx = fmaxf(mx, __shfl_xor(mx, msk, 64));
            const float mnew = fmaxf(m_i[r], mx);
            sc[r] = __expf(m_i[r] - mnew);
            m_i[r] = mnew;
            float ssum = 0.f;
#pragma unroll
            for (int f = 0; f < 4; f++) {
                const float p = __expf(s[f][r] - mnew);
                pr[f][r] = p;
                ssum += p;
            }
#pragma unroll
            for (int msk = 1; msk < 16; msk <<= 1) ssum += __shfl_xor(ssum, msk, 64);
            l_i[r] = l_i[r] * sc[r] + ssum;
        }
#pragma unroll
        for (int f2 = 0; f2 < 6; f2++)
#pragma unroll
            for (int r = 0; r < 4; r++) o[f2][r] *= sc[r];

#pragma unroll
        for (int f = 0; f < 4; f++)
#pragma unroll
            for (int r = 0; r < 4; r++)
                Ps[w][l4 * 4 + r][f * 16 + l15] = (_Float16)pr[f][r];

#pragma unroll
        for (int kc2 = 0; kc2 < 2; kc2++) {
            h8 pa = ld8h(&Ps[w][l15][kc2 * 32 + l4 * 8]);
#pragma unroll
            for (int f2 = 0; f2 < 6; f2++) {
                h8 vb = ld8h(&Vs[buf][f2 * 16 + l15][kc2 * 32 + l4 * 8]);
                o[f2] = __builtin_amdgcn_mfma_f32_16x16x32_f16(pa, vb, o[f2], 0, 0, 0);
            }
        }
    }

#pragma unroll
    for (int r = 0; r < 4; r++) {
        const float inv = 1.0f / l_i[r];
        const size_t row = (size_t)(q0 + w * 16 + l4 * 4 + r) * 3072 + h * 96;
#pragma unroll
        for (int f2 = 0; f2 < 6; f2++)
            Oh[row + f2 * 16 + l15] = (_Float16)(o[f2][r] * inv);
    }
}

// ---------------------------------------------------------------------------
extern "C" void kernel_launch(void* const* d_in, const int* in_sizes, int n_in,
                              void* d_out, int out_size, void* d_ws, size_t ws_size,
                              hipStream_t stream) {
    const float* x = (const float*)d_in[0];
    const float* w_qkv = (const float*)d_in[1];
    const float* w_o = (const float*)d_in[2];
    const float* sf = (const float*)d_in[3];
    float* out = (float*)d_out;
    char* ws = (char*)d_ws;

    _Float16* wqkvh = (_Float16*)(ws);
    _Float16* Qh = (_Float16*)(ws);
    _Float16* Kh = (_Float16*)(ws + 12582912);
    _Float16* Vth = (_Float16*)(ws + 25165824);
    _Float16* Oh = (_Float16*)(ws + 37748736);
    float* qkv = (float*)(ws + 56623104);
    _Float16* xh = (_Float16*)(ws + 132120576);
    _Float16* woh = (_Float16*)(ws + 144703488);

    const float rope_scale = (float)sqrt(1.0 + log(131072.0 / 4096.0) / log(4096.0));
    const float attn_scale = (float)(1.0 / sqrt(96.0));

    convert_half<<<3072, 256, 0, stream>>>(x, xh, 786432);
    convert_half<<<13824, 256, 0, stream>>>(w_qkv, wqkvh, 3538944);
    gemm_fp16<<<dim3(72, 16), 256, 0, stream>>>(xh, wqkvh, qkv, 2048, 9216, 3072);
    rope_half<<<49152, 256, 0, stream>>>(qkv, sf, Qh, Kh, rope_scale, attn_scale);
    vtrans<<<dim3(32, 32), 256, 0, stream>>>(qkv, Vth);
    convert_half<<<4608, 256, 0, stream>>>(w_o, woh, 1179648);
    attn_mfma<<<dim3(32, 32), 256, 0, stream>>>(Qh, Kh, Vth, Oh);
    gemm_fp16<<<dim3(24, 16), 256, 0, stream>>>(Oh, woh, out, 2048, 3072, 3072);
}